// Round 3
// baseline (745.916 us; speedup 1.0000x reference)
//
#include <hip/hip_runtime.h>
#include <math.h>

#define D 64
#define MIN_NORM 1e-15f
#define NBINS 64

#define RCP(x)  __builtin_amdgcn_rcpf(x)
#define RSQ(x)  __builtin_amdgcn_rsqf(x)

// ---------------- DPP butterfly within 16-lane rows ----------------
template <int CTRL>
__device__ __forceinline__ float dpp_sum_step(float v) {
    int iv = __builtin_bit_cast(int, v);
    int sh = __builtin_amdgcn_update_dpp(0, iv, CTRL, 0xf, 0xf, true);
    return v + __builtin_bit_cast(float, sh);
}
#define DPP_XOR1  0xB1   // quad_perm [1,0,3,2]
#define DPP_XOR2  0x4E   // quad_perm [2,3,0,1]
#define DPP_HMIR  0x141  // row_half_mirror
#define DPP_MIR   0x140  // row_mirror

__device__ __forceinline__ float row16_sum(float v) {
    v = dpp_sum_step<DPP_XOR1>(v);
    v = dpp_sum_step<DPP_XOR2>(v);
    v = dpp_sum_step<DPP_HMIR>(v);
    v = dpp_sum_step<DPP_MIR>(v);
    return v;
}

// ---------------- fast transcendentals (args >= 0) ----------------

__device__ __forceinline__ float fast_tanh_pos(float x) {
    float t = __expf(-2.0f * x);
    return (1.0f - t) * RCP(1.0f + t);
}

__device__ __forceinline__ float fast_atanh(float x) {
    return 0.5f * __logf((1.0f + x) * RCP(1.0f - x));
}

// ---------------- RGAT head kernel: 16 lanes/head, CSR edge loop ----------

__global__ __launch_bounds__(256) void rgat_head_kernel(
    const float* __restrict__ ent, const float* __restrict__ rel,
    const int* __restrict__ erow_ptr, const int2* __restrict__ pair_e,
    const int* __restrict__ headperm,
    const float* __restrict__ prev_res,
    float* __restrict__ ent_out, float* __restrict__ res_out,
    int n_ent, int write_ent)
{
    int g = blockIdx.x * 16 + (threadIdx.x >> 4);
    if (g >= n_ent) return;
    int sub = threadIdx.x & 15;
    int h = headperm[g];

    const float* hp = ent + (size_t)h * D + sub;
    float hex = hp[0], hey = hp[16], hez = hp[32], hew = hp[48];
    float HE2 = row16_sum(hex*hex + hey*hey + hez*hez + hew*hew);

    // ---- head-only chain (hoisted) ----
    float HE2g = fmaxf(HE2, 1e-30f);
    float rNhe = RSQ(HE2g);
    float Nhe  = HE2g * rNhe;
    float a = fast_tanh_pos(Nhe) * rNhe;
    float HH2 = a * a * HE2;
    float mterm = fmaxf(1.0f - HH2, MIN_NORM);   // = 2/lam
    float rmterm = RCP(mterm);

    float ax = 0.0f, ay = 0.0f, az = 0.0f, aw = 0.0f;
    int s = erow_ptr[h];
    int e = erow_ptr[h + 1];

    for (int i = s; i < e; ++i) {
        long long pv = __builtin_nontemporal_load((const long long*)(pair_e + i));
        int tcol = (int)(pv & 0xffffffffLL);
        int rrow = (int)(pv >> 32) - 1;
        const float* tp = ent + (size_t)tcol * D + sub;
        const float* rp = rel + (size_t)rrow * D + sub;
        float tex = tp[0], tey = tp[16], tez = tp[32], tew = tp[48];
        float rex = rp[0], rey = rp[16], rez = rp[32], rew = rp[48];

        float TE2 = row16_sum(tex*tex + tey*tey + tez*tez + tew*tew);
        float RE2 = row16_sum(rex*rex + rey*rey + rez*rez + rew*rew);
        float HT  = row16_sum(hex*tex + hey*tey + hez*tez + hew*tew);
        float HR  = row16_sum(hex*rex + hey*rey + hez*rez + hew*rew);
        float TR  = row16_sum(tex*rex + tey*rey + tez*rez + tew*rew);

        float S2 = TE2 + 2.0f * TR + RE2;
        float ricci_k = 1e-7f * RSQ(fmaxf(S2, 1e-24f));

        float TE2g = fmaxf(TE2, 1e-30f);
        float rNte = RSQ(TE2g);
        float b = fast_tanh_pos(TE2g * rNte * rmterm) * rNte;
        float RE2g = fmaxf(RE2, 1e-30f);
        float rNre = RSQ(RE2g);
        float c = fast_tanh_pos(RE2g * rNre * rmterm) * rNre;

        float y2t = b * b * TE2, xyt = a * b * HT;
        float A1 = 1.0f + 2.0f * xyt + y2t, B1 = 1.0f - HH2;
        float r_d1 = RCP(fmaxf(1.0f + 2.0f * xyt + HH2 * y2t, MIN_NORM));
        float p1 = A1 * a * r_d1, q1 = B1 * b * r_d1;
        float HT2 = fmaxf((A1*A1*HH2 + 2.0f*A1*B1*xyt + B1*B1*y2t) * r_d1 * r_d1, 0.0f);

        float y2r = c * c * RE2, xyr = a * c * HR;
        float A2 = 1.0f + 2.0f * xyr + y2r, B2 = 1.0f - HH2;
        float r_d2 = RCP(fmaxf(1.0f + 2.0f * xyr + HH2 * y2r, MIN_NORM));
        float p2 = A2 * a * r_d2, q2 = B2 * c * r_d2;
        float HR2 = fmaxf((A2*A2*HH2 + 2.0f*A2*B2*xyr + B2*B2*y2r) * r_d2 * r_d2, 0.0f);

        float xy3 = p1*p2*HE2 + p1*q2*HR + q1*p2*HT + q1*q2*TR;
        float A3 = 1.0f + 2.0f * xy3 + HR2, B3 = 1.0f - HT2;
        float r_d3 = RCP(fmaxf(1.0f + 2.0f * xy3 + HT2 * HR2, MIN_NORM));
        float al = (A3 * p1 + B3 * p2) * r_d3;
        float be = A3 * q1 * r_d3;
        float ga = B3 * q2 * r_d3;
        float R2 = fmaxf((A3*A3*HT2 + 2.0f*A3*B3*xy3 + B3*B3*HR2) * r_d3 * r_d3, 0.0f);

        float R2g = fmaxf(R2, 1e-30f);
        float rNr = RSQ(R2g);
        float Nr  = R2g * rNr;
        const float maxn = 1.0f - 1e-3f;
        if (Nr > maxn) {
            float sc = maxn * rNr;
            al *= sc; be *= sc; ga *= sc;
            R2 = maxn * maxn;
        }

        float dhr = a * (al * HE2 + be * HT + ga * HR);
        float xy4 = -dhr;
        float A4 = 1.0f + 2.0f * xy4 + R2, B4 = 1.0f - HH2;
        float r_d4 = RCP(fmaxf(1.0f + 2.0f * xy4 + HH2 * R2, MIN_NORM));
        float sh = (-A4 * a + B4 * al) * r_d4;
        float st = B4 * be * r_d4;
        float sr = B4 * ga * r_d4;
        float SUB2 = fmaxf((A4*A4*HH2 + 2.0f*A4*B4*xy4 + B4*B4*R2) * r_d4 * r_d4, 0.0f);

        float SUB2g = fmaxf(SUB2, 1e-30f);
        float rNsub = RSQ(SUB2g);
        float Nsub  = SUB2g * rNsub;
        float k = mterm * fast_atanh(fminf(Nsub, 1.0f - 1e-5f)) * rNsub;

        float kh = k * sh;
        float kt = k * st + ricci_k;
        float kr = k * sr + ricci_k;

        ax += fmaxf(kh*hex + kt*tex + kr*rex, 0.0f);
        ay += fmaxf(kh*hey + kt*tey + kr*rey, 0.0f);
        az += fmaxf(kh*hez + kt*tez + kr*rez, 0.0f);
        aw += fmaxf(kh*hew + kt*tew + kr*rew, 0.0f);
    }

    // ---- fused finalize: mean -> l2norm -> residual ----
    float rc = RCP(fmaxf((float)(e - s), 1.0f));
    float mx = ax*rc, my = ay*rc, mz = az*rc, mw = aw*rc;
    float M2 = row16_sum(mx*mx + my*my + mz*mz + mw*mw);
    float rn = RSQ(fmaxf(M2, 1e-24f));
    mx *= rn; my *= rn; mz *= rn; mw *= rn;

    if (write_ent) {
        float* ep = ent_out + (size_t)h * D + sub;
        ep[0] = mx; ep[16] = my; ep[32] = mz; ep[48] = mw;
    }
    const float* pp = prev_res + (size_t)h * D + sub;
    float* rp2 = res_out + (size_t)h * D + sub;
    rp2[0]  = 0.5f*pp[0]  + mx;
    rp2[16] = 0.5f*pp[16] + my;
    rp2[32] = 0.5f*pp[32] + mz;
    rp2[48] = 0.5f*pp[48] + mw;
}

// ---------------- degree counting sort (64 bins, descending) ----------------

__global__ __launch_bounds__(256) void deg_hist_kernel(
    const int* __restrict__ erow_ptr, int* __restrict__ dbins, int n_heads)
{
    __shared__ int lbin[NBINS];
    int tid = threadIdx.x;
    if (tid < NBINS) lbin[tid] = 0;
    __syncthreads();
    int h = blockIdx.x * 256 + tid;
    if (h < n_heads) {
        int d = min(erow_ptr[h + 1] - erow_ptr[h], NBINS - 1);
        atomicAdd(&lbin[d], 1);
    }
    __syncthreads();
    if (tid < NBINS) { int c = lbin[tid]; if (c) atomicAdd(&dbins[tid], c); }
}

// single wave: descending-order bin bases (largest degree at position 0)
__global__ void deg_scan_kernel(const int* __restrict__ dbins, int* __restrict__ bin_cursor)
{
    int tid = threadIdx.x;   // 64 threads
    int v = dbins[tid];
    int incl = v;
#pragma unroll
    for (int off = 1; off < 64; off <<= 1) {
        int u = __shfl_up(incl, off, 64);
        if (tid >= off) incl += u;
    }
    int T = __shfl(incl, 63, 64);
    bin_cursor[tid] = T - incl;   // descending layout: bin 63 first
}

__global__ __launch_bounds__(256) void deg_scatter_kernel(
    const int* __restrict__ erow_ptr, int* __restrict__ bin_cursor,
    int* __restrict__ headperm, int n_heads)
{
    __shared__ int lbin[NBINS];
    __shared__ int lbase[NBINS];
    int tid = threadIdx.x;
    if (tid < NBINS) lbin[tid] = 0;
    __syncthreads();
    int h = blockIdx.x * 256 + tid;
    int b = 0, lpos = 0;
    bool act = (h < n_heads);
    if (act) {
        b = min(erow_ptr[h + 1] - erow_ptr[h], NBINS - 1);
        lpos = atomicAdd(&lbin[b], 1);
    }
    __syncthreads();
    if (tid < NBINS) { int c = lbin[tid]; lbase[tid] = c ? atomicAdd(&bin_cursor[tid], c) : 0; }
    __syncthreads();
    if (act) headperm[lbase[b] + lpos] = h;
}

// ---------------- concat: init GCN input buffer only (out composed in L2) ----

__global__ void concat_init_kernel(const float4* __restrict__ u,
                                   const float4* __restrict__ res,
                                   float4* __restrict__ bufA,
                                   int user4, int total4)
{
    int i = blockIdx.x * blockDim.x + threadIdx.x;
    if (i >= total4) return;
    float4 v = (i < user4) ? u[i] : res[i - user4];
    bufA[i] = v;
}

// ---------------- CSR build: histogram -> 3-phase scan -> scatter ----------------

__global__ void hist_kernel(const int* __restrict__ row, int* __restrict__ counts, int nnz)
{
    int i = blockIdx.x * blockDim.x + threadIdx.x;
    if (i < nnz) atomicAdd(&counts[__builtin_nontemporal_load(row + i)], 1);
}

// phase 1: per-block (1024 elems) local exclusive scan + block total
__global__ __launch_bounds__(256) void block_scan_kernel(
    const int* __restrict__ counts, int* __restrict__ local_scan,
    int* __restrict__ block_sums, int n)
{
    __shared__ int wsum[4];
    int tid  = threadIdx.x;
    int lane = tid & 63;
    int wave = tid >> 6;
    int base = blockIdx.x * 1024 + tid * 4;

    int4 v = make_int4(0, 0, 0, 0);
    if (base + 3 < n) {
        v = *(const int4*)(counts + base);
    } else {
        if (base + 0 < n) v.x = counts[base + 0];
        if (base + 1 < n) v.y = counts[base + 1];
        if (base + 2 < n) v.z = counts[base + 2];
        if (base + 3 < n) v.w = counts[base + 3];
    }
    int total = v.x + v.y + v.z + v.w;

    int incl = total;
#pragma unroll
    for (int off = 1; off < 64; off <<= 1) {
        int u = __shfl_up(incl, off, 64);
        if (lane >= off) incl += u;
    }
    if (lane == 63) wsum[wave] = incl;
    __syncthreads();
    int woff = 0;
    for (int w = 0; w < wave; ++w) woff += wsum[w];
    int excl = woff + incl - total;

    if (tid == 255) block_sums[blockIdx.x] = woff + incl;

    int p0 = excl;
    int p1 = p0 + v.x;
    int p2 = p1 + v.y;
    int p3 = p2 + v.z;
    if (base + 3 < n) {
        *(int4*)(local_scan + base) = make_int4(p0, p1, p2, p3);
    } else {
        if (base + 0 < n) local_scan[base + 0] = p0;
        if (base + 1 < n) local_scan[base + 1] = p1;
        if (base + 2 < n) local_scan[base + 2] = p2;
        if (base + 3 < n) local_scan[base + 3] = p3;
    }
}

// phase 2: single block scans block totals (nb <= 256) -> exclusive offsets
__global__ __launch_bounds__(256) void scan_blocksums_kernel(
    const int* __restrict__ block_sums, int* __restrict__ block_offs,
    int* __restrict__ row_ptr, int n, int nb)
{
    __shared__ int lds[256];
    int tid = threadIdx.x;
    int v = (tid < nb) ? block_sums[tid] : 0;
    lds[tid] = v;
    __syncthreads();
    for (int off = 1; off < 256; off <<= 1) {
        int t = (tid >= off) ? lds[tid - off] : 0;
        __syncthreads();
        lds[tid] += t;
        __syncthreads();
    }
    block_offs[tid] = lds[tid] - v;
    if (tid == nb - 1) row_ptr[n] = lds[tid];
}

// phase 3: add block offsets, materialize row_ptr + cursor
__global__ void apply_offsets_kernel(const int* __restrict__ local_scan,
                                     const int* __restrict__ block_offs,
                                     int* __restrict__ row_ptr,
                                     int* __restrict__ cursor, int n)
{
    int i = blockIdx.x * blockDim.x + threadIdx.x;
    if (i >= n) return;
    int v = local_scan[i] + block_offs[i >> 10];
    row_ptr[i] = v;
    cursor[i]  = v;
}

// XCD-phased scatter (write-combining via per-XCD L2 ownership of pair slices)
__global__ __launch_bounds__(256) void scatter_phase_kernel(
    const int* __restrict__ row, const int* __restrict__ col,
    const float* __restrict__ val,
    int* __restrict__ cursor, int2* __restrict__ pair, int nnz, int rpp)
{
    int phase = blockIdx.x & 7;
    int i = (blockIdx.x >> 3) * 256 + threadIdx.x;
    if (i >= nnz) return;
    int r = __builtin_nontemporal_load(row + i);
    int lo = phase * rpp;
    if ((unsigned)(r - lo) < (unsigned)rpp) {
        int c = __builtin_nontemporal_load(col + i);
        float v = __builtin_nontemporal_load(val + i);
        int pos = atomicAdd(&cursor[r], 1);
        pair[pos] = make_int2(c, __float_as_int(v));
    }
}

// ---------------- gather SpMM layer 1: nxt = A*cur (no out traffic) --------

__device__ __forceinline__ void spmm_row_acc(
    const int2* __restrict__ pair, const float* __restrict__ cur,
    int s, int e, int lane, float& accout)
{
    float acc0 = 0.0f, acc1 = 0.0f, acc2 = 0.0f, acc3 = 0.0f;
    float acc4 = 0.0f, acc5 = 0.0f, acc6 = 0.0f, acc7 = 0.0f;
    int i = s;
    for (; i + 8 <= e; i += 8) {
        long long q0 = __builtin_nontemporal_load((const long long*)(pair + i + 0));
        long long q1 = __builtin_nontemporal_load((const long long*)(pair + i + 1));
        long long q2 = __builtin_nontemporal_load((const long long*)(pair + i + 2));
        long long q3 = __builtin_nontemporal_load((const long long*)(pair + i + 3));
        long long q4 = __builtin_nontemporal_load((const long long*)(pair + i + 4));
        long long q5 = __builtin_nontemporal_load((const long long*)(pair + i + 5));
        long long q6 = __builtin_nontemporal_load((const long long*)(pair + i + 6));
        long long q7 = __builtin_nontemporal_load((const long long*)(pair + i + 7));
        float x0 = cur[(size_t)(int)(q0 & 0xffffffffLL) * D + lane];
        float x1 = cur[(size_t)(int)(q1 & 0xffffffffLL) * D + lane];
        float x2 = cur[(size_t)(int)(q2 & 0xffffffffLL) * D + lane];
        float x3 = cur[(size_t)(int)(q3 & 0xffffffffLL) * D + lane];
        float x4 = cur[(size_t)(int)(q4 & 0xffffffffLL) * D + lane];
        float x5 = cur[(size_t)(int)(q5 & 0xffffffffLL) * D + lane];
        float x6 = cur[(size_t)(int)(q6 & 0xffffffffLL) * D + lane];
        float x7 = cur[(size_t)(int)(q7 & 0xffffffffLL) * D + lane];
        acc0 = fmaf(__int_as_float((int)(q0 >> 32)), x0, acc0);
        acc1 = fmaf(__int_as_float((int)(q1 >> 32)), x1, acc1);
        acc2 = fmaf(__int_as_float((int)(q2 >> 32)), x2, acc2);
        acc3 = fmaf(__int_as_float((int)(q3 >> 32)), x3, acc3);
        acc4 = fmaf(__int_as_float((int)(q4 >> 32)), x4, acc4);
        acc5 = fmaf(__int_as_float((int)(q5 >> 32)), x5, acc5);
        acc6 = fmaf(__int_as_float((int)(q6 >> 32)), x6, acc6);
        acc7 = fmaf(__int_as_float((int)(q7 >> 32)), x7, acc7);
    }
    for (; i + 4 <= e; i += 4) {
        long long q0 = __builtin_nontemporal_load((const long long*)(pair + i + 0));
        long long q1 = __builtin_nontemporal_load((const long long*)(pair + i + 1));
        long long q2 = __builtin_nontemporal_load((const long long*)(pair + i + 2));
        long long q3 = __builtin_nontemporal_load((const long long*)(pair + i + 3));
        float x0 = cur[(size_t)(int)(q0 & 0xffffffffLL) * D + lane];
        float x1 = cur[(size_t)(int)(q1 & 0xffffffffLL) * D + lane];
        float x2 = cur[(size_t)(int)(q2 & 0xffffffffLL) * D + lane];
        float x3 = cur[(size_t)(int)(q3 & 0xffffffffLL) * D + lane];
        acc0 = fmaf(__int_as_float((int)(q0 >> 32)), x0, acc0);
        acc1 = fmaf(__int_as_float((int)(q1 >> 32)), x1, acc1);
        acc2 = fmaf(__int_as_float((int)(q2 >> 32)), x2, acc2);
        acc3 = fmaf(__int_as_float((int)(q3 >> 32)), x3, acc3);
    }
    for (; i < e; ++i) {
        long long q0 = __builtin_nontemporal_load((const long long*)(pair + i));
        acc0 = fmaf(__int_as_float((int)(q0 >> 32)),
                    cur[(size_t)(int)(q0 & 0xffffffffLL) * D + lane], acc0);
    }
    accout = ((acc0 + acc1) + (acc2 + acc3)) + ((acc4 + acc5) + (acc6 + acc7));
}

__global__ __launch_bounds__(256) void spmm_l1_kernel(
    const int* __restrict__ row_ptr, const int2* __restrict__ pair,
    const float* __restrict__ cur, float* __restrict__ nxt, int n_rows)
{
    int row = blockIdx.x * 4 + (threadIdx.x >> 6);
    if (row >= n_rows) return;
    int lane = threadIdx.x & 63;
    int s = row_ptr[row];
    int e = row_ptr[row + 1];
    float acc;
    spmm_row_acc(pair, cur, s, e, lane, acc);
    nxt[(size_t)row * D + lane] = acc;
}

// layer 2 with fused epilogue: out = embeds + cur1 + A*cur1  (no nxt write)
__global__ __launch_bounds__(256) void spmm_l2_kernel(
    const int* __restrict__ row_ptr, const int2* __restrict__ pair,
    const float* __restrict__ cur1, const float* __restrict__ embeds,
    float* __restrict__ out, int n_rows)
{
    int row = blockIdx.x * 4 + (threadIdx.x >> 6);
    if (row >= n_rows) return;
    int lane = threadIdx.x & 63;
    int s = row_ptr[row];
    int e = row_ptr[row + 1];
    float acc;
    spmm_row_acc(pair, cur1, s, e, lane, acc);
    size_t idx = (size_t)row * D + lane;
    float emb = __builtin_nontemporal_load(embeds + idx);
    float c1  = cur1[idx];
    __builtin_nontemporal_store(emb + c1 + acc, out + idx);
}

// ---------------- launch ----------------

extern "C" void kernel_launch(void* const* d_in, const int* in_sizes, int n_in,
                              void* d_out, int out_size, void* d_ws, size_t ws_size,
                              hipStream_t stream)
{
    const float* uE      = (const float*)d_in[0];
    const float* eE      = (const float*)d_in[1];
    const float* rE      = (const float*)d_in[2];
    const float* adj_val = (const float*)d_in[3];
    const int*   e_head  = (const int*)d_in[4];
    const int*   e_tail  = (const int*)d_in[5];
    const int*   e_type  = (const int*)d_in[6];
    const int*   a_row   = (const int*)d_in[7];
    const int*   a_col   = (const int*)d_in[8];

    const int n_user  = in_sizes[0] / D;   // 100000
    const int n_ent   = in_sizes[1] / D;   // 200000
    const int nnz     = in_sizes[3];       // 2000000
    const int n_edges = in_sizes[4];       // 500000
    const int n_rows  = out_size / D;      // 150000

    float* ws = (float*)d_ws;
    const size_t entElems = (size_t)n_ent * D;           // 12.8M floats
    float* ent1    = ws;                                  // [n_ent][D]; later GCN bufA
    float* ent_res = ws + entElems;                       // [n_ent][D]; later GCN bufB
    int*   r3      = (int*)(ws + 2 * entElems);           // scratch: edge-CSR then adj-CSR

    // ---- edge-CSR (by head) + degree-sort layout (alive during hops) ----
    const int nep = n_ent + 4;                            // padded, keeps 16B alignment
    int*  erow_ptr = r3;                                  // n_ent+1
    int*  ecursor  = erow_ptr + nep;                      // n_ent+1 (counts/cursor)
    int2* pair_e   = (int2*)(ecursor + nep);              // n_edges (tail, type-bits)
    int*  headperm = (int*)(pair_e + n_edges);            // n_ent
    int*  elocal   = headperm + n_ent;                    // n_ent
    int*  ebsums   = elocal + n_ent;                      // 256
    int*  eboffs   = ebsums + 256;                        // 256
    int*  dbins    = eboffs + 256;                        // 64
    int*  bincur   = dbins + NBINS;                       // 64

    // ---- adj-CSR layout (alive during GCN; overlaps edge-CSR, sequential) ----
    int*  row_ptr    = r3;                                // n_rows+1
    int*  cursor     = row_ptr + (n_rows + 4);            // n_rows+1
    int2* pair       = (int2*)(cursor + n_rows + 4);      // nnz
    int*  local_scan = (int*)(pair + nnz);                // n_rows
    int*  block_sums = local_scan + n_rows;               // 256
    int*  block_offs = block_sums + 256;                  // 256

    float* out = (float*)d_out;

    // ================= edge-CSR build + degree sort (once) =================
    const int enb = (n_ent + 1023) / 1024;                // 196 <= 256
    hipMemsetAsync(ecursor, 0, (size_t)nep * sizeof(int), stream);
    hipMemsetAsync(dbins, 0, 2 * NBINS * sizeof(int), stream);
    hist_kernel<<<(n_edges + 255) / 256, 256, 0, stream>>>(e_head, ecursor, n_edges);
    block_scan_kernel<<<enb, 256, 0, stream>>>(ecursor, elocal, ebsums, n_ent);
    scan_blocksums_kernel<<<1, 256, 0, stream>>>(ebsums, eboffs, erow_ptr, n_ent, enb);
    apply_offsets_kernel<<<(n_ent + 255) / 256, 256, 0, stream>>>(elocal, eboffs,
                                                                  erow_ptr, ecursor, n_ent);
    const int erpp = (n_ent + 7) / 8;
    scatter_phase_kernel<<<((n_edges + 255) / 256) * 8, 256, 0, stream>>>(
        e_head, e_tail, (const float*)e_type, ecursor, pair_e, n_edges, erpp);
    deg_hist_kernel<<<(n_ent + 255) / 256, 256, 0, stream>>>(erow_ptr, dbins, n_ent);
    deg_scan_kernel<<<1, 64, 0, stream>>>(dbins, bincur);
    deg_scatter_kernel<<<(n_ent + 255) / 256, 256, 0, stream>>>(erow_ptr, bincur,
                                                                headperm, n_ent);

    // ================= RGAT hops (no atomics, no memset, fused finalize) ====
    const int head_blocks = (n_ent + 15) / 16;
    rgat_head_kernel<<<head_blocks, 256, 0, stream>>>(eE, rE, erow_ptr, pair_e, headperm,
                                                      eE, ent1, ent_res, n_ent, 1);
    rgat_head_kernel<<<head_blocks, 256, 0, stream>>>(ent1, rE, erow_ptr, pair_e, headperm,
                                                      ent_res, ent1, ent_res, n_ent, 0);

    // ================= GCN =================
    float* bufA = ent1;      // embeds (concat target); gather source for L1
    float* bufB = ent_res;   // cur1 (L1 output); gather source + row stream for L2

    const int total4 = n_rows * (D / 4);
    const int user4  = n_user * (D / 4);

    concat_init_kernel<<<(total4 + 255) / 256, 256, 0, stream>>>(
        (const float4*)uE, (const float4*)ent_res, (float4*)bufA, user4, total4);

    // build CSR of adj (reused by both layers) — overwrites dead edge-CSR
    const int nb = (n_rows + 1023) / 1024;   // 147 (<=256)
    hipMemsetAsync(cursor, 0, (size_t)(n_rows + 1) * sizeof(int), stream);
    hist_kernel<<<(nnz + 255) / 256, 256, 0, stream>>>(a_row, cursor, nnz);
    block_scan_kernel<<<nb, 256, 0, stream>>>(cursor, local_scan, block_sums, n_rows);
    scan_blocksums_kernel<<<1, 256, 0, stream>>>(block_sums, block_offs, row_ptr, n_rows, nb);
    apply_offsets_kernel<<<(n_rows + 255) / 256, 256, 0, stream>>>(local_scan, block_offs,
                                                                   row_ptr, cursor, n_rows);
    const int rpp = (n_rows + 7) / 8;
    scatter_phase_kernel<<<((nnz + 255) / 256) * 8, 256, 0, stream>>>(
        a_row, a_col, adj_val, cursor, pair, nnz, rpp);

    const int row_blocks = (n_rows + 3) / 4;
    // layer 1: bufB = A*bufA  (note: concat consumed ent_res before this overwrites it)
    spmm_l1_kernel<<<row_blocks, 256, 0, stream>>>(row_ptr, pair, bufA, bufB, n_rows);
    // layer 2: out = bufA + bufB + A*bufB
    spmm_l2_kernel<<<row_blocks, 256, 0, stream>>>(row_ptr, pair, bufB, bufA, out, n_rows);
}

// Round 5
// 709.772 us; speedup vs baseline: 1.0509x; 1.0509x over previous
//
#include <hip/hip_runtime.h>
#include <math.h>

#define D 64
#define MIN_NORM 1e-15f
#define NBINS 64

#define RCP(x)  __builtin_amdgcn_rcpf(x)
#define RSQ(x)  __builtin_amdgcn_rsqf(x)

// ---------------- DPP butterfly within 16-lane rows ----------------
template <int CTRL>
__device__ __forceinline__ float dpp_sum_step(float v) {
    int iv = __builtin_bit_cast(int, v);
    int sh = __builtin_amdgcn_update_dpp(0, iv, CTRL, 0xf, 0xf, true);
    return v + __builtin_bit_cast(float, sh);
}
#define DPP_XOR1  0xB1   // quad_perm [1,0,3,2]
#define DPP_XOR2  0x4E   // quad_perm [2,3,0,1]
#define DPP_HMIR  0x141  // row_half_mirror
#define DPP_MIR   0x140  // row_mirror

__device__ __forceinline__ float row16_sum(float v) {
    v = dpp_sum_step<DPP_XOR1>(v);
    v = dpp_sum_step<DPP_XOR2>(v);
    v = dpp_sum_step<DPP_HMIR>(v);
    v = dpp_sum_step<DPP_MIR>(v);
    return v;
}

// ---------------- fast transcendentals (args >= 0) ----------------

__device__ __forceinline__ float fast_tanh_pos(float x) {
    float t = __expf(-2.0f * x);
    return (1.0f - t) * RCP(1.0f + t);
}

__device__ __forceinline__ float fast_atanh(float x) {
    return 0.5f * __logf((1.0f + x) * RCP(1.0f - x));
}

// ---------------- RGAT head kernel: 16 lanes/head, CSR edge loop ----------

__global__ __launch_bounds__(256) void rgat_head_kernel(
    const float* __restrict__ ent, const float* __restrict__ rel,
    const int* __restrict__ erow_ptr, const int2* __restrict__ pair_e,
    const int* __restrict__ headperm,
    const float* __restrict__ prev_res,
    float* __restrict__ ent_out, float* __restrict__ res_out,
    int n_ent, int write_ent)
{
    int g = blockIdx.x * 16 + (threadIdx.x >> 4);
    if (g >= n_ent) return;
    int sub = threadIdx.x & 15;
    int h = headperm[g];

    const float* hp = ent + (size_t)h * D + sub;
    float hex = hp[0], hey = hp[16], hez = hp[32], hew = hp[48];
    float HE2 = row16_sum(hex*hex + hey*hey + hez*hez + hew*hew);

    // ---- head-only chain (hoisted) ----
    float HE2g = fmaxf(HE2, 1e-30f);
    float rNhe = RSQ(HE2g);
    float Nhe  = HE2g * rNhe;
    float a = fast_tanh_pos(Nhe) * rNhe;
    float HH2 = a * a * HE2;
    float mterm = fmaxf(1.0f - HH2, MIN_NORM);   // = 2/lam
    float rmterm = RCP(mterm);

    float ax = 0.0f, ay = 0.0f, az = 0.0f, aw = 0.0f;
    int s = erow_ptr[h];
    int e = erow_ptr[h + 1];

    for (int i = s; i < e; ++i) {
        int2 pe = pair_e[i];
        int tcol = pe.x;
        int rrow = pe.y - 1;
        const float* tp = ent + (size_t)tcol * D + sub;
        const float* rp = rel + (size_t)rrow * D + sub;
        float tex = tp[0], tey = tp[16], tez = tp[32], tew = tp[48];
        float rex = rp[0], rey = rp[16], rez = rp[32], rew = rp[48];

        float TE2 = row16_sum(tex*tex + tey*tey + tez*tez + tew*tew);
        float RE2 = row16_sum(rex*rex + rey*rey + rez*rez + rew*rew);
        float HT  = row16_sum(hex*tex + hey*tey + hez*tez + hew*tew);
        float HR  = row16_sum(hex*rex + hey*rey + hez*rez + hew*rew);
        float TR  = row16_sum(tex*rex + tey*rey + tez*rez + tew*rew);

        float S2 = TE2 + 2.0f * TR + RE2;
        float ricci_k = 1e-7f * RSQ(fmaxf(S2, 1e-24f));

        float TE2g = fmaxf(TE2, 1e-30f);
        float rNte = RSQ(TE2g);
        float b = fast_tanh_pos(TE2g * rNte * rmterm) * rNte;
        float RE2g = fmaxf(RE2, 1e-30f);
        float rNre = RSQ(RE2g);
        float c = fast_tanh_pos(RE2g * rNre * rmterm) * rNre;

        float y2t = b * b * TE2, xyt = a * b * HT;
        float A1 = 1.0f + 2.0f * xyt + y2t, B1 = 1.0f - HH2;
        float r_d1 = RCP(fmaxf(1.0f + 2.0f * xyt + HH2 * y2t, MIN_NORM));
        float p1 = A1 * a * r_d1, q1 = B1 * b * r_d1;
        float HT2 = fmaxf((A1*A1*HH2 + 2.0f*A1*B1*xyt + B1*B1*y2t) * r_d1 * r_d1, 0.0f);

        float y2r = c * c * RE2, xyr = a * c * HR;
        float A2 = 1.0f + 2.0f * xyr + y2r, B2 = 1.0f - HH2;
        float r_d2 = RCP(fmaxf(1.0f + 2.0f * xyr + HH2 * y2r, MIN_NORM));
        float p2 = A2 * a * r_d2, q2 = B2 * c * r_d2;
        float HR2 = fmaxf((A2*A2*HH2 + 2.0f*A2*B2*xyr + B2*B2*y2r) * r_d2 * r_d2, 0.0f);

        float xy3 = p1*p2*HE2 + p1*q2*HR + q1*p2*HT + q1*q2*TR;
        float A3 = 1.0f + 2.0f * xy3 + HR2, B3 = 1.0f - HT2;
        float r_d3 = RCP(fmaxf(1.0f + 2.0f * xy3 + HT2 * HR2, MIN_NORM));
        float al = (A3 * p1 + B3 * p2) * r_d3;
        float be = A3 * q1 * r_d3;
        float ga = B3 * q2 * r_d3;
        float R2 = fmaxf((A3*A3*HT2 + 2.0f*A3*B3*xy3 + B3*B3*HR2) * r_d3 * r_d3, 0.0f);

        float R2g = fmaxf(R2, 1e-30f);
        float rNr = RSQ(R2g);
        float Nr  = R2g * rNr;
        const float maxn = 1.0f - 1e-3f;
        if (Nr > maxn) {
            float sc = maxn * rNr;
            al *= sc; be *= sc; ga *= sc;
            R2 = maxn * maxn;
        }

        float dhr = a * (al * HE2 + be * HT + ga * HR);
        float xy4 = -dhr;
        float A4 = 1.0f + 2.0f * xy4 + R2, B4 = 1.0f - HH2;
        float r_d4 = RCP(fmaxf(1.0f + 2.0f * xy4 + HH2 * R2, MIN_NORM));
        float sh = (-A4 * a + B4 * al) * r_d4;
        float st = B4 * be * r_d4;
        float sr = B4 * ga * r_d4;
        float SUB2 = fmaxf((A4*A4*HH2 + 2.0f*A4*B4*xy4 + B4*B4*R2) * r_d4 * r_d4, 0.0f);

        float SUB2g = fmaxf(SUB2, 1e-30f);
        float rNsub = RSQ(SUB2g);
        float Nsub  = SUB2g * rNsub;
        float k = mterm * fast_atanh(fminf(Nsub, 1.0f - 1e-5f)) * rNsub;

        float kh = k * sh;
        float kt = k * st + ricci_k;
        float kr = k * sr + ricci_k;

        ax += fmaxf(kh*hex + kt*tex + kr*rex, 0.0f);
        ay += fmaxf(kh*hey + kt*tey + kr*rey, 0.0f);
        az += fmaxf(kh*hez + kt*tez + kr*rez, 0.0f);
        aw += fmaxf(kh*hew + kt*tew + kr*rew, 0.0f);
    }

    // ---- fused finalize: mean -> l2norm -> residual ----
    float rc = RCP(fmaxf((float)(e - s), 1.0f));
    float mx = ax*rc, my = ay*rc, mz = az*rc, mw = aw*rc;
    float M2 = row16_sum(mx*mx + my*my + mz*mz + mw*mw);
    float rn = RSQ(fmaxf(M2, 1e-24f));
    mx *= rn; my *= rn; mz *= rn; mw *= rn;

    if (write_ent) {
        float* ep = ent_out + (size_t)h * D + sub;
        ep[0] = mx; ep[16] = my; ep[32] = mz; ep[48] = mw;
    }
    const float* pp = prev_res + (size_t)h * D + sub;
    float* rp2 = res_out + (size_t)h * D + sub;
    rp2[0]  = 0.5f*pp[0]  + mx;
    rp2[16] = 0.5f*pp[16] + my;
    rp2[32] = 0.5f*pp[32] + mz;
    rp2[48] = 0.5f*pp[48] + mw;
}

// ---------------- degree counting sort (64 bins, descending) ----------------

__global__ __launch_bounds__(256) void deg_hist_kernel(
    const int* __restrict__ erow_ptr, int* __restrict__ dbins, int n_heads)
{
    __shared__ int lbin[NBINS];
    int tid = threadIdx.x;
    if (tid < NBINS) lbin[tid] = 0;
    __syncthreads();
    int h = blockIdx.x * 256 + tid;
    if (h < n_heads) {
        int d = min(erow_ptr[h + 1] - erow_ptr[h], NBINS - 1);
        atomicAdd(&lbin[d], 1);
    }
    __syncthreads();
    if (tid < NBINS) { int c = lbin[tid]; if (c) atomicAdd(&dbins[tid], c); }
}

// single wave: descending-order bin bases (largest degree at position 0)
__global__ void deg_scan_kernel(const int* __restrict__ dbins, int* __restrict__ bin_cursor)
{
    int tid = threadIdx.x;   // 64 threads
    int v = dbins[tid];
    int incl = v;
#pragma unroll
    for (int off = 1; off < 64; off <<= 1) {
        int u = __shfl_up(incl, off, 64);
        if (tid >= off) incl += u;
    }
    int T = __shfl(incl, 63, 64);
    bin_cursor[tid] = T - incl;   // descending layout: bin 63 first
}

__global__ __launch_bounds__(256) void deg_scatter_kernel(
    const int* __restrict__ erow_ptr, int* __restrict__ bin_cursor,
    int* __restrict__ headperm, int n_heads)
{
    __shared__ int lbin[NBINS];
    __shared__ int lbase[NBINS];
    int tid = threadIdx.x;
    if (tid < NBINS) lbin[tid] = 0;
    __syncthreads();
    int h = blockIdx.x * 256 + tid;
    int b = 0, lpos = 0;
    bool act = (h < n_heads);
    if (act) {
        b = min(erow_ptr[h + 1] - erow_ptr[h], NBINS - 1);
        lpos = atomicAdd(&lbin[b], 1);
    }
    __syncthreads();
    if (tid < NBINS) { int c = lbin[tid]; lbase[tid] = c ? atomicAdd(&bin_cursor[tid], c) : 0; }
    __syncthreads();
    if (act) headperm[lbase[b] + lpos] = h;
}

// ---------------- concat: init GCN input buffer only ----------------

__global__ void concat_init_kernel(const float4* __restrict__ u,
                                   const float4* __restrict__ res,
                                   float4* __restrict__ bufA,
                                   int user4, int total4)
{
    int i = blockIdx.x * blockDim.x + threadIdx.x;
    if (i >= total4) return;
    float4 v = (i < user4) ? u[i] : res[i - user4];
    bufA[i] = v;
}

// ---------------- CSR build: histogram -> 3-phase scan -> scatter ----------------

__global__ void hist_kernel(const int* __restrict__ row, int* __restrict__ counts, int nnz)
{
    int i = blockIdx.x * blockDim.x + threadIdx.x;
    if (i < nnz) atomicAdd(&counts[row[i]], 1);
}

// phase 1: per-block (1024 elems) local exclusive scan + block total
__global__ __launch_bounds__(256) void block_scan_kernel(
    const int* __restrict__ counts, int* __restrict__ local_scan,
    int* __restrict__ block_sums, int n)
{
    __shared__ int wsum[4];
    int tid  = threadIdx.x;
    int lane = tid & 63;
    int wave = tid >> 6;
    int base = blockIdx.x * 1024 + tid * 4;

    int4 v = make_int4(0, 0, 0, 0);
    if (base + 3 < n) {
        v = *(const int4*)(counts + base);
    } else {
        if (base + 0 < n) v.x = counts[base + 0];
        if (base + 1 < n) v.y = counts[base + 1];
        if (base + 2 < n) v.z = counts[base + 2];
        if (base + 3 < n) v.w = counts[base + 3];
    }
    int total = v.x + v.y + v.z + v.w;

    int incl = total;
#pragma unroll
    for (int off = 1; off < 64; off <<= 1) {
        int u = __shfl_up(incl, off, 64);
        if (lane >= off) incl += u;
    }
    if (lane == 63) wsum[wave] = incl;
    __syncthreads();
    int woff = 0;
    for (int w = 0; w < wave; ++w) woff += wsum[w];
    int excl = woff + incl - total;

    if (tid == 255) block_sums[blockIdx.x] = woff + incl;

    int p0 = excl;
    int p1 = p0 + v.x;
    int p2 = p1 + v.y;
    int p3 = p2 + v.z;
    if (base + 3 < n) {
        *(int4*)(local_scan + base) = make_int4(p0, p1, p2, p3);
    } else {
        if (base + 0 < n) local_scan[base + 0] = p0;
        if (base + 1 < n) local_scan[base + 1] = p1;
        if (base + 2 < n) local_scan[base + 2] = p2;
        if (base + 3 < n) local_scan[base + 3] = p3;
    }
}

// phase 2: single block scans block totals (nb <= 256) -> exclusive offsets
__global__ __launch_bounds__(256) void scan_blocksums_kernel(
    const int* __restrict__ block_sums, int* __restrict__ block_offs,
    int* __restrict__ row_ptr, int n, int nb)
{
    __shared__ int lds[256];
    int tid = threadIdx.x;
    int v = (tid < nb) ? block_sums[tid] : 0;
    lds[tid] = v;
    __syncthreads();
    for (int off = 1; off < 256; off <<= 1) {
        int t = (tid >= off) ? lds[tid - off] : 0;
        __syncthreads();
        lds[tid] += t;
        __syncthreads();
    }
    block_offs[tid] = lds[tid] - v;
    if (tid == nb - 1) row_ptr[n] = lds[tid];
}

// phase 3: add block offsets, materialize row_ptr + cursor
__global__ void apply_offsets_kernel(const int* __restrict__ local_scan,
                                     const int* __restrict__ block_offs,
                                     int* __restrict__ row_ptr,
                                     int* __restrict__ cursor, int n)
{
    int i = blockIdx.x * blockDim.x + threadIdx.x;
    if (i >= n) return;
    int v = local_scan[i] + block_offs[i >> 10];
    row_ptr[i] = v;
    cursor[i]  = v;
}

// XCD-phased scatter (write-combining via per-XCD L2 ownership of pair slices)
__global__ __launch_bounds__(256) void scatter_phase_kernel(
    const int* __restrict__ row, const int* __restrict__ col,
    const float* __restrict__ val,
    int* __restrict__ cursor, int2* __restrict__ pair, int nnz, int rpp)
{
    int phase = blockIdx.x & 7;
    int i = (blockIdx.x >> 3) * 256 + threadIdx.x;
    if (i >= nnz) return;
    int r = row[i];
    int lo = phase * rpp;
    if ((unsigned)(r - lo) < (unsigned)rpp) {
        int c = __builtin_nontemporal_load(col + i);
        float v = __builtin_nontemporal_load(val + i);
        int pos = atomicAdd(&cursor[r], 1);
        pair[pos] = make_int2(c, __float_as_int(v));
    }
}

// ---------------- gather SpMM: wave per row, readlane-broadcast pairs ------
// One vector load grabs the row's whole (col,val) segment (lane i ->
// pair[s+i]); v_readlane moves each col/val to SGPRs, so all gathers for a
// row are independent scalar-base loads issued back-to-back (no per-8
// pair-load dependency). Lanes past cnt clamp to a valid col; their val is
// zeroed (branch-free).

__device__ __forceinline__ float spmm_row_gather(
    const int2* __restrict__ pair, const float* __restrict__ cur,
    int s, int e, int lane)
{
    int cnt = e - s;
    if (cnt <= 0) return 0.0f;
    int nv = min(cnt, 64);
    int2 q = pair[s + min(lane, nv - 1)];

    float acc0 = 0.0f, acc1 = 0.0f, acc2 = 0.0f, acc3 = 0.0f;
    float acc4 = 0.0f, acc5 = 0.0f, acc6 = 0.0f, acc7 = 0.0f;

    for (int base = 0; base < nv; base += 8) {
        int c0 = __builtin_amdgcn_readlane(q.x, base + 0);
        int c1 = __builtin_amdgcn_readlane(q.x, base + 1);
        int c2 = __builtin_amdgcn_readlane(q.x, base + 2);
        int c3 = __builtin_amdgcn_readlane(q.x, base + 3);
        int c4 = __builtin_amdgcn_readlane(q.x, base + 4);
        int c5 = __builtin_amdgcn_readlane(q.x, base + 5);
        int c6 = __builtin_amdgcn_readlane(q.x, base + 6);
        int c7 = __builtin_amdgcn_readlane(q.x, base + 7);
        float x0 = cur[(size_t)c0 * D + lane];
        float x1 = cur[(size_t)c1 * D + lane];
        float x2 = cur[(size_t)c2 * D + lane];
        float x3 = cur[(size_t)c3 * D + lane];
        float x4 = cur[(size_t)c4 * D + lane];
        float x5 = cur[(size_t)c5 * D + lane];
        float x6 = cur[(size_t)c6 * D + lane];
        float x7 = cur[(size_t)c7 * D + lane];
        float v0 = (base + 0 < nv) ? __int_as_float(__builtin_amdgcn_readlane(q.y, base + 0)) : 0.0f;
        float v1 = (base + 1 < nv) ? __int_as_float(__builtin_amdgcn_readlane(q.y, base + 1)) : 0.0f;
        float v2 = (base + 2 < nv) ? __int_as_float(__builtin_amdgcn_readlane(q.y, base + 2)) : 0.0f;
        float v3 = (base + 3 < nv) ? __int_as_float(__builtin_amdgcn_readlane(q.y, base + 3)) : 0.0f;
        float v4 = (base + 4 < nv) ? __int_as_float(__builtin_amdgcn_readlane(q.y, base + 4)) : 0.0f;
        float v5 = (base + 5 < nv) ? __int_as_float(__builtin_amdgcn_readlane(q.y, base + 5)) : 0.0f;
        float v6 = (base + 6 < nv) ? __int_as_float(__builtin_amdgcn_readlane(q.y, base + 6)) : 0.0f;
        float v7 = (base + 7 < nv) ? __int_as_float(__builtin_amdgcn_readlane(q.y, base + 7)) : 0.0f;
        acc0 = fmaf(v0, x0, acc0);
        acc1 = fmaf(v1, x1, acc1);
        acc2 = fmaf(v2, x2, acc2);
        acc3 = fmaf(v3, x3, acc3);
        acc4 = fmaf(v4, x4, acc4);
        acc5 = fmaf(v5, x5, acc5);
        acc6 = fmaf(v6, x6, acc6);
        acc7 = fmaf(v7, x7, acc7);
    }
    // overflow tail (cnt > 64: statistically impossible for Poisson(13.3),
    // kept for safety)
    for (int i = s + 64; i < e; ++i) {
        int2 p = pair[i];
        acc0 = fmaf(__int_as_float(p.y), cur[(size_t)p.x * D + lane], acc0);
    }
    return ((acc0 + acc1) + (acc2 + acc3)) + ((acc4 + acc5) + (acc6 + acc7));
}

__global__ __launch_bounds__(256) void spmm_l1_kernel(
    const int* __restrict__ row_ptr, const int2* __restrict__ pair,
    const float* __restrict__ cur, float* __restrict__ nxt, int n_rows)
{
    int row = blockIdx.x * 4 + (threadIdx.x >> 6);
    if (row >= n_rows) return;
    int lane = threadIdx.x & 63;
    int s = row_ptr[row];
    int e = row_ptr[row + 1];
    float acc = spmm_row_gather(pair, cur, s, e, lane);
    nxt[(size_t)row * D + lane] = acc;
}

// layer 2 with fused epilogue: out = embeds + cur1 + A*cur1
__global__ __launch_bounds__(256) void spmm_l2_kernel(
    const int* __restrict__ row_ptr, const int2* __restrict__ pair,
    const float* __restrict__ cur1, const float* __restrict__ embeds,
    float* __restrict__ out, int n_rows)
{
    int row = blockIdx.x * 4 + (threadIdx.x >> 6);
    if (row >= n_rows) return;
    int lane = threadIdx.x & 63;
    int s = row_ptr[row];
    int e = row_ptr[row + 1];
    float acc = spmm_row_gather(pair, cur1, s, e, lane);
    size_t idx = (size_t)row * D + lane;
    float emb = __builtin_nontemporal_load(embeds + idx);
    float c1  = cur1[idx];
    __builtin_nontemporal_store(emb + c1 + acc, out + idx);
}

// ---------------- launch ----------------

extern "C" void kernel_launch(void* const* d_in, const int* in_sizes, int n_in,
                              void* d_out, int out_size, void* d_ws, size_t ws_size,
                              hipStream_t stream)
{
    const float* uE      = (const float*)d_in[0];
    const float* eE      = (const float*)d_in[1];
    const float* rE      = (const float*)d_in[2];
    const float* adj_val = (const float*)d_in[3];
    const int*   e_head  = (const int*)d_in[4];
    const int*   e_tail  = (const int*)d_in[5];
    const int*   e_type  = (const int*)d_in[6];
    const int*   a_row   = (const int*)d_in[7];
    const int*   a_col   = (const int*)d_in[8];

    const int n_user  = in_sizes[0] / D;   // 100000
    const int n_ent   = in_sizes[1] / D;   // 200000
    const int nnz     = in_sizes[3];       // 2000000
    const int n_edges = in_sizes[4];       // 500000
    const int n_rows  = out_size / D;      // 150000

    float* ws = (float*)d_ws;
    const size_t entElems = (size_t)n_ent * D;           // 12.8M floats
    float* ent1    = ws;                                  // [n_ent][D]; later GCN bufA
    float* ent_res = ws + entElems;                       // [n_ent][D]; later GCN bufB
    int*   r3      = (int*)(ws + 2 * entElems);           // scratch: edge-CSR then adj-CSR

    // ---- edge-CSR (by head) + degree-sort layout (alive during hops) ----
    const int nep = n_ent + 4;                            // padded, keeps 16B alignment
    int*  erow_ptr = r3;                                  // n_ent+1
    int*  ecursor  = erow_ptr + nep;                      // n_ent+1 (counts/cursor)
    int2* pair_e   = (int2*)(ecursor + nep);              // n_edges (tail, type)
    int*  headperm = (int*)(pair_e + n_edges);            // n_ent
    int*  elocal   = headperm + n_ent;                    // n_ent
    int*  ebsums   = elocal + n_ent;                      // 256
    int*  eboffs   = ebsums + 256;                        // 256
    int*  dbins    = eboffs + 256;                        // 64
    int*  bincur   = dbins + NBINS;                       // 64

    // ---- adj-CSR layout (alive during GCN; overlaps edge-CSR, sequential) ----
    int*  row_ptr    = r3;                                // n_rows+1
    int*  cursor     = row_ptr + (n_rows + 4);            // n_rows+1
    int2* pair       = (int2*)(cursor + n_rows + 4);      // nnz
    int*  local_scan = (int*)(pair + nnz);                // n_rows
    int*  block_sums = local_scan + n_rows;               // 256
    int*  block_offs = block_sums + 256;                  // 256

    float* out = (float*)d_out;

    // ================= edge-CSR build + degree sort (once) =================
    const int enb = (n_ent + 1023) / 1024;                // 196 <= 256
    hipMemsetAsync(ecursor, 0, (size_t)nep * sizeof(int), stream);
    hipMemsetAsync(dbins, 0, 2 * NBINS * sizeof(int), stream);
    hist_kernel<<<(n_edges + 255) / 256, 256, 0, stream>>>(e_head, ecursor, n_edges);
    block_scan_kernel<<<enb, 256, 0, stream>>>(ecursor, elocal, ebsums, n_ent);
    scan_blocksums_kernel<<<1, 256, 0, stream>>>(ebsums, eboffs, erow_ptr, n_ent, enb);
    apply_offsets_kernel<<<(n_ent + 255) / 256, 256, 0, stream>>>(elocal, eboffs,
                                                                  erow_ptr, ecursor, n_ent);
    const int erpp = (n_ent + 7) / 8;
    scatter_phase_kernel<<<((n_edges + 255) / 256) * 8, 256, 0, stream>>>(
        e_head, e_tail, (const float*)e_type, ecursor, pair_e, n_edges, erpp);
    deg_hist_kernel<<<(n_ent + 255) / 256, 256, 0, stream>>>(erow_ptr, dbins, n_ent);
    deg_scan_kernel<<<1, 64, 0, stream>>>(dbins, bincur);
    deg_scatter_kernel<<<(n_ent + 255) / 256, 256, 0, stream>>>(erow_ptr, bincur,
                                                                headperm, n_ent);

    // ================= RGAT hops (no atomics, no memset, fused finalize) ====
    const int head_blocks = (n_ent + 15) / 16;
    rgat_head_kernel<<<head_blocks, 256, 0, stream>>>(eE, rE, erow_ptr, pair_e, headperm,
                                                      eE, ent1, ent_res, n_ent, 1);
    rgat_head_kernel<<<head_blocks, 256, 0, stream>>>(ent1, rE, erow_ptr, pair_e, headperm,
                                                      ent_res, ent1, ent_res, n_ent, 0);

    // ================= GCN =================
    float* bufA = ent1;      // embeds (concat target); gather source for L1
    float* bufB = ent_res;   // cur1 (L1 output); gather source + row stream for L2

    const int total4 = n_rows * (D / 4);
    const int user4  = n_user * (D / 4);

    concat_init_kernel<<<(total4 + 255) / 256, 256, 0, stream>>>(
        (const float4*)uE, (const float4*)ent_res, (float4*)bufA, user4, total4);

    // build CSR of adj (reused by both layers) — overwrites dead edge-CSR
    const int nb = (n_rows + 1023) / 1024;   // 147 (<=256)
    hipMemsetAsync(cursor, 0, (size_t)(n_rows + 1) * sizeof(int), stream);
    hist_kernel<<<(nnz + 255) / 256, 256, 0, stream>>>(a_row, cursor, nnz);
    block_scan_kernel<<<nb, 256, 0, stream>>>(cursor, local_scan, block_sums, n_rows);
    scan_blocksums_kernel<<<1, 256, 0, stream>>>(block_sums, block_offs, row_ptr, n_rows, nb);
    apply_offsets_kernel<<<(n_rows + 255) / 256, 256, 0, stream>>>(local_scan, block_offs,
                                                                   row_ptr, cursor, n_rows);
    const int rpp = (n_rows + 7) / 8;
    scatter_phase_kernel<<<((nnz + 255) / 256) * 8, 256, 0, stream>>>(
        a_row, a_col, adj_val, cursor, pair, nnz, rpp);

    const int row_blocks = (n_rows + 3) / 4;
    // layer 1: bufB = A*bufA  (concat consumed ent_res before this overwrites it)
    spmm_l1_kernel<<<row_blocks, 256, 0, stream>>>(row_ptr, pair, bufA, bufB, n_rows);
    // layer 2: out = bufA + bufB + A*bufB
    spmm_l2_kernel<<<row_blocks, 256, 0, stream>>>(row_ptr, pair, bufB, bufA, out, n_rows);
}

// Round 6
// 704.630 us; speedup vs baseline: 1.0586x; 1.0073x over previous
//
#include <hip/hip_runtime.h>
#include <math.h>

#define D 64
#define MIN_NORM 1e-15f
#define NBINS 64
#define MAXBKT 1024
#define L1_TILE 4096

#define RCP(x)  __builtin_amdgcn_rcpf(x)
#define RSQ(x)  __builtin_amdgcn_rsqf(x)

// ---------------- DPP butterfly within 16-lane rows ----------------
template <int CTRL>
__device__ __forceinline__ float dpp_sum_step(float v) {
    int iv = __builtin_bit_cast(int, v);
    int sh = __builtin_amdgcn_update_dpp(0, iv, CTRL, 0xf, 0xf, true);
    return v + __builtin_bit_cast(float, sh);
}
#define DPP_XOR1  0xB1   // quad_perm [1,0,3,2]
#define DPP_XOR2  0x4E   // quad_perm [2,3,0,1]
#define DPP_HMIR  0x141  // row_half_mirror
#define DPP_MIR   0x140  // row_mirror

__device__ __forceinline__ float row16_sum(float v) {
    v = dpp_sum_step<DPP_XOR1>(v);
    v = dpp_sum_step<DPP_XOR2>(v);
    v = dpp_sum_step<DPP_HMIR>(v);
    v = dpp_sum_step<DPP_MIR>(v);
    return v;
}

// ---------------- fast transcendentals (args >= 0) ----------------

__device__ __forceinline__ float fast_tanh_pos(float x) {
    float t = __expf(-2.0f * x);
    return (1.0f - t) * RCP(1.0f + t);
}

__device__ __forceinline__ float fast_atanh(float x) {
    return 0.5f * __logf((1.0f + x) * RCP(1.0f - x));
}

// ---------------- RGAT head kernel: 16 lanes/head, CSR edge loop ----------

__global__ __launch_bounds__(256) void rgat_head_kernel(
    const float* __restrict__ ent, const float* __restrict__ rel,
    const int* __restrict__ erow_ptr, const int2* __restrict__ pair_e,
    const int* __restrict__ headperm,
    const float* __restrict__ prev_res,
    float* __restrict__ ent_out, float* __restrict__ res_out,
    int n_ent, int write_ent)
{
    int g = blockIdx.x * 16 + (threadIdx.x >> 4);
    if (g >= n_ent) return;
    int sub = threadIdx.x & 15;
    int h = headperm[g];

    const float* hp = ent + (size_t)h * D + sub;
    float hex = hp[0], hey = hp[16], hez = hp[32], hew = hp[48];
    float HE2 = row16_sum(hex*hex + hey*hey + hez*hez + hew*hew);

    // ---- head-only chain (hoisted) ----
    float HE2g = fmaxf(HE2, 1e-30f);
    float rNhe = RSQ(HE2g);
    float Nhe  = HE2g * rNhe;
    float a = fast_tanh_pos(Nhe) * rNhe;
    float HH2 = a * a * HE2;
    float mterm = fmaxf(1.0f - HH2, MIN_NORM);   // = 2/lam
    float rmterm = RCP(mterm);

    float ax = 0.0f, ay = 0.0f, az = 0.0f, aw = 0.0f;
    int s = erow_ptr[h];
    int e = erow_ptr[h + 1];

    for (int i = s; i < e; ++i) {
        int2 pe = pair_e[i];
        int tcol = pe.x;
        int rrow = pe.y - 1;
        const float* tp = ent + (size_t)tcol * D + sub;
        const float* rp = rel + (size_t)rrow * D + sub;
        float tex = tp[0], tey = tp[16], tez = tp[32], tew = tp[48];
        float rex = rp[0], rey = rp[16], rez = rp[32], rew = rp[48];

        float TE2 = row16_sum(tex*tex + tey*tey + tez*tez + tew*tew);
        float RE2 = row16_sum(rex*rex + rey*rey + rez*rez + rew*rew);
        float HT  = row16_sum(hex*tex + hey*tey + hez*tez + hew*tew);
        float HR  = row16_sum(hex*rex + hey*rey + hez*rez + hew*rew);
        float TR  = row16_sum(tex*rex + tey*rey + tez*rez + tew*rew);

        float S2 = TE2 + 2.0f * TR + RE2;
        float ricci_k = 1e-7f * RSQ(fmaxf(S2, 1e-24f));

        float TE2g = fmaxf(TE2, 1e-30f);
        float rNte = RSQ(TE2g);
        float b = fast_tanh_pos(TE2g * rNte * rmterm) * rNte;
        float RE2g = fmaxf(RE2, 1e-30f);
        float rNre = RSQ(RE2g);
        float c = fast_tanh_pos(RE2g * rNre * rmterm) * rNre;

        float y2t = b * b * TE2, xyt = a * b * HT;
        float A1 = 1.0f + 2.0f * xyt + y2t, B1 = 1.0f - HH2;
        float r_d1 = RCP(fmaxf(1.0f + 2.0f * xyt + HH2 * y2t, MIN_NORM));
        float p1 = A1 * a * r_d1, q1 = B1 * b * r_d1;
        float HT2 = fmaxf((A1*A1*HH2 + 2.0f*A1*B1*xyt + B1*B1*y2t) * r_d1 * r_d1, 0.0f);

        float y2r = c * c * RE2, xyr = a * c * HR;
        float A2 = 1.0f + 2.0f * xyr + y2r, B2 = 1.0f - HH2;
        float r_d2 = RCP(fmaxf(1.0f + 2.0f * xyr + HH2 * y2r, MIN_NORM));
        float p2 = A2 * a * r_d2, q2 = B2 * c * r_d2;
        float HR2 = fmaxf((A2*A2*HH2 + 2.0f*A2*B2*xyr + B2*B2*y2r) * r_d2 * r_d2, 0.0f);

        float xy3 = p1*p2*HE2 + p1*q2*HR + q1*p2*HT + q1*q2*TR;
        float A3 = 1.0f + 2.0f * xy3 + HR2, B3 = 1.0f - HT2;
        float r_d3 = RCP(fmaxf(1.0f + 2.0f * xy3 + HT2 * HR2, MIN_NORM));
        float al = (A3 * p1 + B3 * p2) * r_d3;
        float be = A3 * q1 * r_d3;
        float ga = B3 * q2 * r_d3;
        float R2 = fmaxf((A3*A3*HT2 + 2.0f*A3*B3*xy3 + B3*B3*HR2) * r_d3 * r_d3, 0.0f);

        float R2g = fmaxf(R2, 1e-30f);
        float rNr = RSQ(R2g);
        float Nr  = R2g * rNr;
        const float maxn = 1.0f - 1e-3f;
        if (Nr > maxn) {
            float sc = maxn * rNr;
            al *= sc; be *= sc; ga *= sc;
            R2 = maxn * maxn;
        }

        float dhr = a * (al * HE2 + be * HT + ga * HR);
        float xy4 = -dhr;
        float A4 = 1.0f + 2.0f * xy4 + R2, B4 = 1.0f - HH2;
        float r_d4 = RCP(fmaxf(1.0f + 2.0f * xy4 + HH2 * R2, MIN_NORM));
        float sh = (-A4 * a + B4 * al) * r_d4;
        float st = B4 * be * r_d4;
        float sr = B4 * ga * r_d4;
        float SUB2 = fmaxf((A4*A4*HH2 + 2.0f*A4*B4*xy4 + B4*B4*R2) * r_d4 * r_d4, 0.0f);

        float SUB2g = fmaxf(SUB2, 1e-30f);
        float rNsub = RSQ(SUB2g);
        float Nsub  = SUB2g * rNsub;
        float k = mterm * fast_atanh(fminf(Nsub, 1.0f - 1e-5f)) * rNsub;

        float kh = k * sh;
        float kt = k * st + ricci_k;
        float kr = k * sr + ricci_k;

        ax += fmaxf(kh*hex + kt*tex + kr*rex, 0.0f);
        ay += fmaxf(kh*hey + kt*tey + kr*rey, 0.0f);
        az += fmaxf(kh*hez + kt*tez + kr*rez, 0.0f);
        aw += fmaxf(kh*hew + kt*tew + kr*rew, 0.0f);
    }

    // ---- fused finalize: mean -> l2norm -> residual ----
    float rc = RCP(fmaxf((float)(e - s), 1.0f));
    float mx = ax*rc, my = ay*rc, mz = az*rc, mw = aw*rc;
    float M2 = row16_sum(mx*mx + my*my + mz*mz + mw*mw);
    float rn = RSQ(fmaxf(M2, 1e-24f));
    mx *= rn; my *= rn; mz *= rn; mw *= rn;

    if (write_ent) {
        float* ep = ent_out + (size_t)h * D + sub;
        ep[0] = mx; ep[16] = my; ep[32] = mz; ep[48] = mw;
    }
    const float* pp = prev_res + (size_t)h * D + sub;
    float* rp2 = res_out + (size_t)h * D + sub;
    rp2[0]  = 0.5f*pp[0]  + mx;
    rp2[16] = 0.5f*pp[16] + my;
    rp2[32] = 0.5f*pp[32] + mz;
    rp2[48] = 0.5f*pp[48] + mw;
}

// ---------------- degree counting sort (64 bins, descending) ----------------

__global__ __launch_bounds__(256) void deg_hist_kernel(
    const int* __restrict__ erow_ptr, int* __restrict__ dbins, int n_heads)
{
    __shared__ int lbin[NBINS];
    int tid = threadIdx.x;
    if (tid < NBINS) lbin[tid] = 0;
    __syncthreads();
    int h = blockIdx.x * 256 + tid;
    if (h < n_heads) {
        int d = min(erow_ptr[h + 1] - erow_ptr[h], NBINS - 1);
        atomicAdd(&lbin[d], 1);
    }
    __syncthreads();
    if (tid < NBINS) { int c = lbin[tid]; if (c) atomicAdd(&dbins[tid], c); }
}

// single wave: descending-order bin bases (largest degree at position 0)
__global__ void deg_scan_kernel(const int* __restrict__ dbins, int* __restrict__ bin_cursor)
{
    int tid = threadIdx.x;   // 64 threads
    int v = dbins[tid];
    int incl = v;
#pragma unroll
    for (int off = 1; off < 64; off <<= 1) {
        int u = __shfl_up(incl, off, 64);
        if (tid >= off) incl += u;
    }
    int T = __shfl(incl, 63, 64);
    bin_cursor[tid] = T - incl;   // descending layout: bin 63 first
}

__global__ __launch_bounds__(256) void deg_scatter_kernel(
    const int* __restrict__ erow_ptr, int* __restrict__ bin_cursor,
    int* __restrict__ headperm, int n_heads)
{
    __shared__ int lbin[NBINS];
    __shared__ int lbase[NBINS];
    int tid = threadIdx.x;
    if (tid < NBINS) lbin[tid] = 0;
    __syncthreads();
    int h = blockIdx.x * 256 + tid;
    int b = 0, lpos = 0;
    bool act = (h < n_heads);
    if (act) {
        b = min(erow_ptr[h + 1] - erow_ptr[h], NBINS - 1);
        lpos = atomicAdd(&lbin[b], 1);
    }
    __syncthreads();
    if (tid < NBINS) { int c = lbin[tid]; lbase[tid] = c ? atomicAdd(&bin_cursor[tid], c) : 0; }
    __syncthreads();
    if (act) headperm[lbase[b] + lpos] = h;
}

// ---------------- concat: init GCN input buffer only ----------------

__global__ void concat_init_kernel(const float4* __restrict__ u,
                                   const float4* __restrict__ res,
                                   float4* __restrict__ bufA,
                                   int user4, int total4)
{
    int i = blockIdx.x * blockDim.x + threadIdx.x;
    if (i >= total4) return;
    float4 v = (i < user4) ? u[i] : res[i - user4];
    bufA[i] = v;
}

// ---------------- CSR build: histogram -> 3-phase scan ----------------

__global__ void hist_kernel(const int* __restrict__ row, int* __restrict__ counts, int nnz)
{
    int i = blockIdx.x * blockDim.x + threadIdx.x;
    if (i < nnz) atomicAdd(&counts[row[i]], 1);
}

// phase 1: per-block (1024 elems) local exclusive scan + block total
__global__ __launch_bounds__(256) void block_scan_kernel(
    const int* __restrict__ counts, int* __restrict__ local_scan,
    int* __restrict__ block_sums, int n)
{
    __shared__ int wsum[4];
    int tid  = threadIdx.x;
    int lane = tid & 63;
    int wave = tid >> 6;
    int base = blockIdx.x * 1024 + tid * 4;

    int4 v = make_int4(0, 0, 0, 0);
    if (base + 3 < n) {
        v = *(const int4*)(counts + base);
    } else {
        if (base + 0 < n) v.x = counts[base + 0];
        if (base + 1 < n) v.y = counts[base + 1];
        if (base + 2 < n) v.z = counts[base + 2];
        if (base + 3 < n) v.w = counts[base + 3];
    }
    int total = v.x + v.y + v.z + v.w;

    int incl = total;
#pragma unroll
    for (int off = 1; off < 64; off <<= 1) {
        int u = __shfl_up(incl, off, 64);
        if (lane >= off) incl += u;
    }
    if (lane == 63) wsum[wave] = incl;
    __syncthreads();
    int woff = 0;
    for (int w = 0; w < wave; ++w) woff += wsum[w];
    int excl = woff + incl - total;

    if (tid == 255) block_sums[blockIdx.x] = woff + incl;

    int p0 = excl;
    int p1 = p0 + v.x;
    int p2 = p1 + v.y;
    int p3 = p2 + v.z;
    if (base + 3 < n) {
        *(int4*)(local_scan + base) = make_int4(p0, p1, p2, p3);
    } else {
        if (base + 0 < n) local_scan[base + 0] = p0;
        if (base + 1 < n) local_scan[base + 1] = p1;
        if (base + 2 < n) local_scan[base + 2] = p2;
        if (base + 3 < n) local_scan[base + 3] = p3;
    }
}

// phase 2: single block scans block totals (nb <= 256) -> exclusive offsets
__global__ __launch_bounds__(256) void scan_blocksums_kernel(
    const int* __restrict__ block_sums, int* __restrict__ block_offs,
    int* __restrict__ row_ptr, int n, int nb)
{
    __shared__ int lds[256];
    int tid = threadIdx.x;
    int v = (tid < nb) ? block_sums[tid] : 0;
    lds[tid] = v;
    __syncthreads();
    for (int off = 1; off < 256; off <<= 1) {
        int t = (tid >= off) ? lds[tid - off] : 0;
        __syncthreads();
        lds[tid] += t;
        __syncthreads();
    }
    block_offs[tid] = lds[tid] - v;
    if (tid == nb - 1) row_ptr[n] = lds[tid];
}

// phase 3: add block offsets, materialize row_ptr + cursor
__global__ void apply_offsets_kernel(const int* __restrict__ local_scan,
                                     const int* __restrict__ block_offs,
                                     int* __restrict__ row_ptr,
                                     int* __restrict__ cursor, int n)
{
    int i = blockIdx.x * blockDim.x + threadIdx.x;
    if (i >= n) return;
    int v = local_scan[i] + block_offs[i >> 10];
    row_ptr[i] = v;
    cursor[i]  = v;
}

// ---------------- two-level bucket scatter (replaces random scatter) -------
// Level 1: LDS counting-sort of 4096-entry tiles by bucket (row>>8), flush
// bucket-contiguous runs (~7 entries = 56B, sequential) into bkt[], which is
// grouped by 256-row windows. Level 2: one block per window places its ~27KB
// segment at exact CSR positions — destination lines are block-private and
// written within the block's lifetime -> full L2 write combining.

__global__ void bktcur_init_kernel(const int* __restrict__ row_ptr,
                                   int* __restrict__ bktcur, int nbkt, int nkeys)
{
    int b = blockIdx.x * 256 + threadIdx.x;
    if (b < nbkt) bktcur[b] = row_ptr[min(b << 8, nkeys)];
}

__global__ __launch_bounds__(256) void bucket_l1_kernel(
    const int* __restrict__ key, const int* __restrict__ col,
    const int* __restrict__ vbits,
    int* __restrict__ bktcur, int2* __restrict__ bkt,
    int n, int nbkt)
{
    __shared__ int lcnt[MAXBKT];
    __shared__ int lofs[MAXBKT];
    __shared__ int gofs[MAXBKT];
    __shared__ int lpos[MAXBKT];
    __shared__ int wsum[4];
    __shared__ int2 lent[L1_TILE];
    __shared__ unsigned short lbkt[L1_TILE];

    int tid  = threadIdx.x;
    int lane = tid & 63;
    int wave = tid >> 6;
    int base = blockIdx.x * L1_TILE;
    int cnt_total = min(n - base, L1_TILE);

    for (int b = tid; b < MAXBKT; b += 256) lcnt[b] = 0;
    __syncthreads();

    // pass 1: count
#pragma unroll
    for (int k = 0; k < L1_TILE / 256; ++k) {
        int i = base + k * 256 + tid;
        if (i < n) atomicAdd(&lcnt[key[i] >> 8], 1);
    }
    __syncthreads();

    // prefix over lcnt (4 consecutive buckets per thread, wave scan + LDS)
    int b0 = tid * 4;
    int c0 = lcnt[b0], c1 = lcnt[b0 + 1], c2 = lcnt[b0 + 2], c3 = lcnt[b0 + 3];
    int tot = c0 + c1 + c2 + c3;
    int incl = tot;
#pragma unroll
    for (int off = 1; off < 64; off <<= 1) {
        int u = __shfl_up(incl, off, 64);
        if (lane >= off) incl += u;
    }
    if (lane == 63) wsum[wave] = incl;
    __syncthreads();
    int woff = 0;
    for (int w = 0; w < wave; ++w) woff += wsum[w];
    int excl = woff + incl - tot;
    lofs[b0]     = excl;              lpos[b0]     = excl;
    lofs[b0 + 1] = excl + c0;         lpos[b0 + 1] = excl + c0;
    lofs[b0 + 2] = excl + c0 + c1;    lpos[b0 + 2] = excl + c0 + c1;
    lofs[b0 + 3] = excl + c0 + c1 + c2; lpos[b0 + 3] = excl + c0 + c1 + c2;
    for (int b = tid; b < nbkt; b += 256) {
        int c = lcnt[b];
        gofs[b] = c ? atomicAdd(&bktcur[b], c) : 0;
    }
    __syncthreads();

    // pass 2: place into LDS in bucket order
#pragma unroll
    for (int k = 0; k < L1_TILE / 256; ++k) {
        int i = base + k * 256 + tid;
        if (i < n) {
            int r = key[i];
            int b = r >> 8;
            int p = atomicAdd(&lpos[b], 1);
            lent[p] = make_int2((col[i] << 8) | (r & 255), vbits[i]);
            lbkt[p] = (unsigned short)b;
        }
    }
    __syncthreads();

    // flush: consecutive LDS slots -> consecutive global slots (coalesced runs)
    for (int j = tid; j < cnt_total; j += 256) {
        int b = lbkt[j];
        bkt[gofs[b] + (j - lofs[b])] = lent[j];
    }
}

__global__ __launch_bounds__(256) void place_l2_kernel(
    const int* __restrict__ row_ptr, const int2* __restrict__ bkt,
    int* __restrict__ cursor, int2* __restrict__ pair, int nkeys)
{
    int b = blockIdx.x;
    int rbase = b << 8;
    int s = row_ptr[min(rbase, nkeys)];
    int e = row_ptr[min(rbase + 256, nkeys)];
    for (int i = s + (int)threadIdx.x; i < e; i += 256) {
        int2 q = bkt[i];
        int pos = atomicAdd(&cursor[rbase + (q.x & 255)], 1);
        pair[pos] = make_int2(q.x >> 8, q.y);
    }
}

// ---------------- gather SpMM: wave per row, readlane-broadcast pairs ------

__device__ __forceinline__ float spmm_row_gather(
    const int2* __restrict__ pair, const float* __restrict__ cur,
    int s, int e, int lane)
{
    int cnt = e - s;
    if (cnt <= 0) return 0.0f;
    int nv = min(cnt, 64);
    int2 q = pair[s + min(lane, nv - 1)];

    float acc0 = 0.0f, acc1 = 0.0f, acc2 = 0.0f, acc3 = 0.0f;
    float acc4 = 0.0f, acc5 = 0.0f, acc6 = 0.0f, acc7 = 0.0f;

    for (int base = 0; base < nv; base += 8) {
        int c0 = __builtin_amdgcn_readlane(q.x, base + 0);
        int c1 = __builtin_amdgcn_readlane(q.x, base + 1);
        int c2 = __builtin_amdgcn_readlane(q.x, base + 2);
        int c3 = __builtin_amdgcn_readlane(q.x, base + 3);
        int c4 = __builtin_amdgcn_readlane(q.x, base + 4);
        int c5 = __builtin_amdgcn_readlane(q.x, base + 5);
        int c6 = __builtin_amdgcn_readlane(q.x, base + 6);
        int c7 = __builtin_amdgcn_readlane(q.x, base + 7);
        float x0 = cur[(size_t)c0 * D + lane];
        float x1 = cur[(size_t)c1 * D + lane];
        float x2 = cur[(size_t)c2 * D + lane];
        float x3 = cur[(size_t)c3 * D + lane];
        float x4 = cur[(size_t)c4 * D + lane];
        float x5 = cur[(size_t)c5 * D + lane];
        float x6 = cur[(size_t)c6 * D + lane];
        float x7 = cur[(size_t)c7 * D + lane];
        float v0 = (base + 0 < nv) ? __int_as_float(__builtin_amdgcn_readlane(q.y, base + 0)) : 0.0f;
        float v1 = (base + 1 < nv) ? __int_as_float(__builtin_amdgcn_readlane(q.y, base + 1)) : 0.0f;
        float v2 = (base + 2 < nv) ? __int_as_float(__builtin_amdgcn_readlane(q.y, base + 2)) : 0.0f;
        float v3 = (base + 3 < nv) ? __int_as_float(__builtin_amdgcn_readlane(q.y, base + 3)) : 0.0f;
        float v4 = (base + 4 < nv) ? __int_as_float(__builtin_amdgcn_readlane(q.y, base + 4)) : 0.0f;
        float v5 = (base + 5 < nv) ? __int_as_float(__builtin_amdgcn_readlane(q.y, base + 5)) : 0.0f;
        float v6 = (base + 6 < nv) ? __int_as_float(__builtin_amdgcn_readlane(q.y, base + 6)) : 0.0f;
        float v7 = (base + 7 < nv) ? __int_as_float(__builtin_amdgcn_readlane(q.y, base + 7)) : 0.0f;
        acc0 = fmaf(v0, x0, acc0);
        acc1 = fmaf(v1, x1, acc1);
        acc2 = fmaf(v2, x2, acc2);
        acc3 = fmaf(v3, x3, acc3);
        acc4 = fmaf(v4, x4, acc4);
        acc5 = fmaf(v5, x5, acc5);
        acc6 = fmaf(v6, x6, acc6);
        acc7 = fmaf(v7, x7, acc7);
    }
    for (int i = s + 64; i < e; ++i) {
        int2 p = pair[i];
        acc0 = fmaf(__int_as_float(p.y), cur[(size_t)p.x * D + lane], acc0);
    }
    return ((acc0 + acc1) + (acc2 + acc3)) + ((acc4 + acc5) + (acc6 + acc7));
}

__global__ __launch_bounds__(256) void spmm_l1_kernel(
    const int* __restrict__ row_ptr, const int2* __restrict__ pair,
    const float* __restrict__ cur, float* __restrict__ nxt, int n_rows)
{
    int row = blockIdx.x * 4 + (threadIdx.x >> 6);
    if (row >= n_rows) return;
    int lane = threadIdx.x & 63;
    int s = row_ptr[row];
    int e = row_ptr[row + 1];
    float acc = spmm_row_gather(pair, cur, s, e, lane);
    nxt[(size_t)row * D + lane] = acc;
}

// layer 2 with fused epilogue: out = embeds + cur1 + A*cur1
__global__ __launch_bounds__(256) void spmm_l2_kernel(
    const int* __restrict__ row_ptr, const int2* __restrict__ pair,
    const float* __restrict__ cur1, const float* __restrict__ embeds,
    float* __restrict__ out, int n_rows)
{
    int row = blockIdx.x * 4 + (threadIdx.x >> 6);
    if (row >= n_rows) return;
    int lane = threadIdx.x & 63;
    int s = row_ptr[row];
    int e = row_ptr[row + 1];
    float acc = spmm_row_gather(pair, cur1, s, e, lane);
    size_t idx = (size_t)row * D + lane;
    float emb = __builtin_nontemporal_load(embeds + idx);
    float c1  = cur1[idx];
    __builtin_nontemporal_store(emb + c1 + acc, out + idx);
}

// ---------------- launch ----------------

extern "C" void kernel_launch(void* const* d_in, const int* in_sizes, int n_in,
                              void* d_out, int out_size, void* d_ws, size_t ws_size,
                              hipStream_t stream)
{
    const float* uE      = (const float*)d_in[0];
    const float* eE      = (const float*)d_in[1];
    const float* rE      = (const float*)d_in[2];
    const float* adj_val = (const float*)d_in[3];
    const int*   e_head  = (const int*)d_in[4];
    const int*   e_tail  = (const int*)d_in[5];
    const int*   e_type  = (const int*)d_in[6];
    const int*   a_row   = (const int*)d_in[7];
    const int*   a_col   = (const int*)d_in[8];

    const int n_user  = in_sizes[0] / D;   // 100000
    const int n_ent   = in_sizes[1] / D;   // 200000
    const int nnz     = in_sizes[3];       // 2000000
    const int n_edges = in_sizes[4];       // 500000
    const int n_rows  = out_size / D;      // 150000

    float* ws = (float*)d_ws;
    const size_t entElems = (size_t)n_ent * D;           // 12.8M floats
    float* ent1    = ws;                                  // [n_ent][D]; later GCN bufA
    float* ent_res = ws + entElems;                       // [n_ent][D]; later GCN bufB
    int*   r3      = (int*)(ws + 2 * entElems);           // scratch: edge-CSR then adj-CSR

    // bkt intermediates alias ent_res (free during both CSR builds:
    // edge build precedes hop1's ent_res write; adj build follows concat's
    // ent_res consumption and precedes spmm_l1's bufB write).
    int2* ebkt = (int2*)ent_res;                          // n_edges int2 (4MB)
    int2* abkt = (int2*)ent_res;                          // nnz int2 (16MB)

    // ---- edge-CSR (by head) + degree-sort layout (alive during hops) ----
    const int nep = n_ent + 4;                            // padded, keeps 16B alignment
    int*  erow_ptr = r3;                                  // n_ent+1
    int*  ecursor  = erow_ptr + nep;                      // n_ent+1 (counts/cursor)
    int2* pair_e   = (int2*)(ecursor + nep);              // n_edges (tail, type)
    int*  headperm = (int*)(pair_e + n_edges);            // n_ent
    int*  elocal   = headperm + n_ent;                    // n_ent
    int*  ebsums   = elocal + n_ent;                      // 256
    int*  eboffs   = ebsums + 256;                        // 256
    int*  dbins    = eboffs + 256;                        // 64
    int*  bincur   = dbins + NBINS;                       // 64
    int*  ebktcur  = bincur + NBINS;                      // <=1024

    // ---- adj-CSR layout (alive during GCN; overlaps edge-CSR, sequential) ----
    int*  row_ptr    = r3;                                // n_rows+1
    int*  cursor     = row_ptr + (n_rows + 4);            // n_rows+1
    int2* pair       = (int2*)(cursor + n_rows + 4);      // nnz
    int*  local_scan = (int*)(pair + nnz);                // n_rows
    int*  block_sums = local_scan + n_rows;               // 256
    int*  block_offs = block_sums + 256;                  // 256
    int*  abktcur    = block_offs + 256;                  // <=1024

    float* out = (float*)d_out;

    // ================= edge-CSR build (two-level bucket scatter) ===========
    const int enb    = (n_ent + 1023) / 1024;             // 196 <= 256
    const int nbkt_e = (n_ent + 255) / 256;               // 782 <= MAXBKT
    hipMemsetAsync(ecursor, 0, (size_t)nep * sizeof(int), stream);
    hipMemsetAsync(dbins, 0, 2 * NBINS * sizeof(int), stream);
    hist_kernel<<<(n_edges + 255) / 256, 256, 0, stream>>>(e_head, ecursor, n_edges);
    block_scan_kernel<<<enb, 256, 0, stream>>>(ecursor, elocal, ebsums, n_ent);
    scan_blocksums_kernel<<<1, 256, 0, stream>>>(ebsums, eboffs, erow_ptr, n_ent, enb);
    apply_offsets_kernel<<<(n_ent + 255) / 256, 256, 0, stream>>>(elocal, eboffs,
                                                                  erow_ptr, ecursor, n_ent);
    bktcur_init_kernel<<<(nbkt_e + 255) / 256, 256, 0, stream>>>(erow_ptr, ebktcur,
                                                                 nbkt_e, n_ent);
    bucket_l1_kernel<<<(n_edges + L1_TILE - 1) / L1_TILE, 256, 0, stream>>>(
        e_head, e_tail, (const int*)e_type, ebktcur, ebkt, n_edges, nbkt_e);
    place_l2_kernel<<<nbkt_e, 256, 0, stream>>>(erow_ptr, ebkt, ecursor, pair_e, n_ent);
    deg_hist_kernel<<<(n_ent + 255) / 256, 256, 0, stream>>>(erow_ptr, dbins, n_ent);
    deg_scan_kernel<<<1, 64, 0, stream>>>(dbins, bincur);
    deg_scatter_kernel<<<(n_ent + 255) / 256, 256, 0, stream>>>(erow_ptr, bincur,
                                                                headperm, n_ent);

    // ================= RGAT hops (no atomics, no memset, fused finalize) ====
    const int head_blocks = (n_ent + 15) / 16;
    rgat_head_kernel<<<head_blocks, 256, 0, stream>>>(eE, rE, erow_ptr, pair_e, headperm,
                                                      eE, ent1, ent_res, n_ent, 1);
    rgat_head_kernel<<<head_blocks, 256, 0, stream>>>(ent1, rE, erow_ptr, pair_e, headperm,
                                                      ent_res, ent1, ent_res, n_ent, 0);

    // ================= GCN =================
    float* bufA = ent1;      // embeds (concat target); gather source for L1
    float* bufB = ent_res;   // cur1 (L1 output); gather source + row stream for L2

    const int total4 = n_rows * (D / 4);
    const int user4  = n_user * (D / 4);

    concat_init_kernel<<<(total4 + 255) / 256, 256, 0, stream>>>(
        (const float4*)uE, (const float4*)ent_res, (float4*)bufA, user4, total4);

    // build CSR of adj (two-level bucket scatter) — overwrites dead edge-CSR
    const int nb     = (n_rows + 1023) / 1024;            // 147 (<=256)
    const int nbkt_a = (n_rows + 255) / 256;              // 586 <= MAXBKT
    hipMemsetAsync(cursor, 0, (size_t)(n_rows + 1) * sizeof(int), stream);
    hist_kernel<<<(nnz + 255) / 256, 256, 0, stream>>>(a_row, cursor, nnz);
    block_scan_kernel<<<nb, 256, 0, stream>>>(cursor, local_scan, block_sums, n_rows);
    scan_blocksums_kernel<<<1, 256, 0, stream>>>(block_sums, block_offs, row_ptr, n_rows, nb);
    apply_offsets_kernel<<<(n_rows + 255) / 256, 256, 0, stream>>>(local_scan, block_offs,
                                                                   row_ptr, cursor, n_rows);
    bktcur_init_kernel<<<(nbkt_a + 255) / 256, 256, 0, stream>>>(row_ptr, abktcur,
                                                                 nbkt_a, n_rows);
    bucket_l1_kernel<<<(nnz + L1_TILE - 1) / L1_TILE, 256, 0, stream>>>(
        a_row, a_col, (const int*)adj_val, abktcur, abkt, nnz, nbkt_a);
    place_l2_kernel<<<nbkt_a, 256, 0, stream>>>(row_ptr, abkt, cursor, pair, n_rows);

    const int row_blocks = (n_rows + 3) / 4;
    // layer 1: bufB = A*bufA  (concat consumed ent_res; abkt also dead by now)
    spmm_l1_kernel<<<row_blocks, 256, 0, stream>>>(row_ptr, pair, bufA, bufB, n_rows);
    // layer 2: out = bufA + bufB + A*bufB
    spmm_l2_kernel<<<row_blocks, 256, 0, stream>>>(row_ptr, pair, bufB, bufA, out, n_rows);
}